// Round 1
// baseline (596.330 us; speedup 1.0000x reference)
//
#include <hip/hip_runtime.h>
#include <math.h>

// Problem constants (setup_inputs is fixed): B=2, H=W=64, N=4096, C=128, K=8, 5 Sinkhorn iters.
#define NPTS 4096

// Workspace layout (float offsets)
#define SZ_S    (2ul*4096ul*4096ul)
#define OFF_U   (SZ_S)                     // 2*4097
#define OFF_V   (OFF_U + 2*4097)           // 2*4097
#define OFF_RN  (OFF_V + 2*4097)           // 16384 (rnA | rnB)
#define OFF_PM  (OFF_RN + 16384)           // 2*16*4096
#define OFF_PS  (OFF_PM + 2*16*4096)       // 2*16*4096
#define OFF_TKV (OFF_PS + 2*16*4096)       // 2*4096*8
#define OFF_TKP (OFF_TKV + 2*4096*8)       // 2*4096*8*2
#define OFF_DP  (OFF_TKP + 2*4096*8*2)     // 2*8*2*4096 (planar [bk][c][n])
#define OFF_GEO (OFF_DP + 2*8*2*4096)      // 2*4096*8
#define OFF_SUM (OFF_GEO + 2*4096*8)       // 24 doubles (48 floats)

#define NORMC   (-9.010913348f)            // -log(8192)
#define MLOG2   (-0.6931471806f)           // log(N)+NORMC = -log(2)

static __device__ __forceinline__ void lse_combine(float& m, float& s, float x) {
    float nm = fmaxf(m, x);
    s = s * __expf(m - nm) + __expf(x - nm);
    m = nm;
}
static __device__ __forceinline__ void lse_merge(float& m, float& s, float m2, float s2) {
    float nm = fmaxf(m, m2);
    s = s * __expf(m - nm) + s2 * __expf(m2 - nm);
    m = nm;
}

// --- 1) inverse L2 norms of feat_A / feat_B rows: rn[0..8191]=A, rn[8192..]=B ---
__global__ __launch_bounds__(256) void norms_kernel(
    const float* __restrict__ fA, const float* __restrict__ fB, float* __restrict__ rn)
{
    int t = threadIdx.x;
    int rowg = blockIdx.x * 4 + (t >> 6);
    int lane = t & 63;
    const float* f = (rowg < 8192) ? fA : fB;
    int r = rowg & 8191;
    float x0 = f[(size_t)r * 128 + lane];
    float x1 = f[(size_t)r * 128 + 64 + lane];
    float s = x0 * x0 + x1 * x1;
    #pragma unroll
    for (int off = 32; off > 0; off >>= 1) s += __shfl_xor(s, off, 64);
    if (lane == 0) rn[rowg] = 1.f / fmaxf(sqrtf(s), 1e-12f);
}

// --- 2) S[b,i,j] = dot(fA[i],fB[j]) * rnA[i]*rnB[j] / temp; 64x64 tile fp32 ---
__global__ __launch_bounds__(256) void gemm_scores(
    const float* __restrict__ fA, const float* __restrict__ fB,
    const float* __restrict__ rn, const float* __restrict__ temp,
    float* __restrict__ S)
{
    int b = blockIdx.z;
    int i0 = blockIdx.y * 64, j0 = blockIdx.x * 64;
    int t = threadIdx.x;
    int tx = t & 15, ty = t >> 4;
    __shared__ __align__(16) float As[16][68];
    __shared__ __align__(16) float Bs[16][68];
    float acc[4][4] = {};
    int lr = t >> 2;          // 0..63: tile row
    int lk = (t & 3) * 4;     // 0,4,8,12: k quad
    const float* pa = fA + ((size_t)(b * 4096 + i0 + lr)) * 128 + lk;
    const float* pb = fB + ((size_t)(b * 4096 + j0 + lr)) * 128 + lk;
    for (int k0 = 0; k0 < 128; k0 += 16) {
        float4 av = *(const float4*)(pa + k0);
        float4 bv = *(const float4*)(pb + k0);
        __syncthreads();
        As[lk + 0][lr] = av.x; As[lk + 1][lr] = av.y; As[lk + 2][lr] = av.z; As[lk + 3][lr] = av.w;
        Bs[lk + 0][lr] = bv.x; Bs[lk + 1][lr] = bv.y; Bs[lk + 2][lr] = bv.z; Bs[lk + 3][lr] = bv.w;
        __syncthreads();
        #pragma unroll
        for (int kk = 0; kk < 16; kk++) {
            float4 a4 = *(const float4*)&As[kk][ty * 4];
            float4 b4 = *(const float4*)&Bs[kk][tx * 4];
            float aa[4] = {a4.x, a4.y, a4.z, a4.w};
            float bb[4] = {b4.x, b4.y, b4.z, b4.w};
            #pragma unroll
            for (int r = 0; r < 4; r++)
                #pragma unroll
                for (int s = 0; s < 4; s++) acc[r][s] += aa[r] * bb[s];
        }
    }
    float invt = 1.0f / temp[0];
    const float* rnA = rn;
    const float* rnB = rn + 8192;
    float4 rb4 = *(const float4*)&rnB[b * 4096 + j0 + tx * 4];
    float rb[4] = {rb4.x, rb4.y, rb4.z, rb4.w};
    #pragma unroll
    for (int r = 0; r < 4; r++) {
        int i = i0 + ty * 4 + r;
        float ra = rnA[b * 4096 + i] * invt;
        float4 ov;
        ov.x = acc[r][0] * ra * rb[0];
        ov.y = acc[r][1] * ra * rb[1];
        ov.z = acc[r][2] * ra * rb[2];
        ov.w = acc[r][3] * ra * rb[3];
        *(float4*)&S[((size_t)(b * 4096 + i)) * 4096 + j0 + tx * 4] = ov;
    }
}

// --- 3a) u[i] = log_mu[i] - LSE_j(Z[i,j] + v[j]); one block per row (incl. dustbin row i=N) ---
__global__ __launch_bounds__(256) void sink_u(
    const float* __restrict__ S, float* __restrict__ u, const float* __restrict__ v,
    const float* __restrict__ dbp)
{
    int row = blockIdx.x;             // 0 .. 2*4097-1
    int b = row / 4097;
    int i = row % 4097;
    int t = threadIdx.x;
    const float* vb = v + b * 4097;
    float db = dbp[0];
    float m = -INFINITY, s = 0.f;
    if (i < 4096) {
        const float* Srow = S + ((size_t)b * 4096 + i) * 4096;
        #pragma unroll 4
        for (int j = t; j < 4096; j += 256) lse_combine(m, s, Srow[j] + vb[j]);
    } else {
        #pragma unroll 4
        for (int j = t; j < 4096; j += 256) lse_combine(m, s, db + vb[j]);
    }
    __shared__ float lm[256], ls[256];
    lm[t] = m; ls[t] = s; __syncthreads();
    for (int off = 128; off > 0; off >>= 1) {
        if (t < off) { float mm = lm[t], ss = ls[t]; lse_merge(mm, ss, lm[t + off], ls[t + off]); lm[t] = mm; ls[t] = ss; }
        __syncthreads();
    }
    if (t == 0) {
        float mm = lm[0], ss = ls[0];
        float tail = (i == 4096 ? 0.f : db) + vb[4096];   // column N entry
        lse_combine(mm, ss, tail);
        float lmu = (i == 4096) ? MLOG2 : NORMC;
        u[b * 4097 + i] = lmu - (mm + __logf(ss));
    }
}

// --- 3b) v partials: per (b, row-chunk rc, column j): online LSE over 256 rows ---
__global__ __launch_bounds__(256) void sink_vA(
    const float* __restrict__ S, const float* __restrict__ u,
    float* __restrict__ pm, float* __restrict__ ps)
{
    int b = blockIdx.z, rc = blockIdx.y;
    int j = blockIdx.x * 256 + threadIdx.x;
    const float* ub = u + b * 4097;
    const float* Sb = S + (size_t)b * 4096 * 4096;
    float m = -INFINITY, s = 0.f;
    int i0 = rc * 256;
    #pragma unroll 4
    for (int i = i0; i < i0 + 256; i++) {
        float x = Sb[(size_t)i * 4096 + j] + ub[i];
        lse_combine(m, s, x);
    }
    pm[(size_t)(b * 16 + rc) * 4096 + j] = m;
    ps[(size_t)(b * 16 + rc) * 4096 + j] = s;
}

// --- 3c) combine partials -> v[j]; block 16 handles dustbin column v[N] ---
__global__ __launch_bounds__(256) void sink_vB(
    const float* __restrict__ pm, const float* __restrict__ ps,
    const float* __restrict__ u, float* __restrict__ v, const float* __restrict__ dbp)
{
    int b = blockIdx.z;
    int t = threadIdx.x;
    const float* ub = u + b * 4097;
    float db = dbp[0];
    __shared__ float lm[256], ls[256];
    if (blockIdx.x < 16) {
        int j = blockIdx.x * 256 + t;
        float m = -INFINITY, s = 0.f;
        #pragma unroll
        for (int rc = 0; rc < 16; rc++) {
            float m2 = pm[(size_t)(b * 16 + rc) * 4096 + j];
            float s2 = ps[(size_t)(b * 16 + rc) * 4096 + j];
            lse_merge(m, s, m2, s2);
        }
        lse_combine(m, s, db + ub[4096]);   // dustbin row contribution
        v[b * 4097 + j] = NORMC - (m + __logf(s));
    } else {
        // column N: LSE( db + u[0..N-1], u[N] )
        float m = -INFINITY, s = 0.f;
        for (int i = t; i < 4096; i += 256) lse_combine(m, s, ub[i]);
        lm[t] = m; ls[t] = s; __syncthreads();
        for (int off = 128; off > 0; off >>= 1) {
            if (t < off) { float mm = lm[t], ss = ls[t]; lse_merge(mm, ss, lm[t + off], ls[t + off]); lm[t] = mm; ls[t] = ss; }
            __syncthreads();
        }
        if (t == 0) {
            float lseu = lm[0] + __logf(ls[0]);
            float a = db + lseu, x2 = ub[4096];
            float mm = fmaxf(a, x2);
            float ssum = __expf(a - mm) + __expf(x2 - mm);
            v[b * 4097 + 4096] = MLOG2 - (mm + __logf(ssum));
        }
    }
}

// --- 4) per-row top-8 of S[i,:]+v[:] (== top-8 of ot_prob); emit vals/pos/disp ---
__global__ __launch_bounds__(256) void topk_kernel(
    const float* __restrict__ S, const float* __restrict__ u, const float* __restrict__ v,
    const float* __restrict__ posA, const float* __restrict__ posB,
    float* __restrict__ tkv, float* __restrict__ tkp, float* __restrict__ dp)
{
    int row = blockIdx.x;             // 0..8191 == b*4096+i
    int b = row >> 12; int i = row & 4095;
    int t = threadIdx.x;
    __shared__ float vals[4096];
    __shared__ float rv[256]; __shared__ int ri[256];
    __shared__ float selv[8]; __shared__ int seli[8];
    const float* Srow = S + (size_t)row * 4096;
    const float* vb = v + b * 4097;
    for (int j = t; j < 4096; j += 256) vals[j] = Srow[j] + vb[j];
    __syncthreads();
    for (int k = 0; k < 8; k++) {
        float lv = -INFINITY; int li = 0x7fffffff;
        for (int j = t; j < 4096; j += 256) {
            float x = vals[j];
            if (x > lv) { lv = x; li = j; }
        }
        rv[t] = lv; ri[t] = li; __syncthreads();
        for (int off = 128; off > 0; off >>= 1) {
            if (t < off) {
                float v2 = rv[t + off]; int i2 = ri[t + off];
                if (v2 > rv[t] || (v2 == rv[t] && i2 < ri[t])) { rv[t] = v2; ri[t] = i2; }
            }
            __syncthreads();
        }
        if (t == 0) { selv[k] = rv[0]; seli[k] = ri[0]; vals[ri[0]] = -INFINITY; }
        __syncthreads();
    }
    if (t < 8) {
        int k = t; int idx = seli[k]; float lv = selv[k];
        float val = __expf(lv + u[b * 4097 + i]);
        float px = posB[((size_t)(b * 4096 + idx)) * 2 + 0];
        float py = posB[((size_t)(b * 4096 + idx)) * 2 + 1];
        float ax = posA[((size_t)(b * 4096 + i)) * 2 + 0];
        float ay = posA[((size_t)(b * 4096 + i)) * 2 + 1];
        size_t base = ((size_t)(b * 4096 + i)) * 8 + k;
        tkv[base] = val;
        tkp[base * 2 + 0] = px; tkp[base * 2 + 1] = py;
        dp[((size_t)(b * 8 + k) * 2 + 0) * 4096 + i] = px - ax;
        dp[((size_t)(b * 8 + k) * 2 + 1) * 4096 + i] = py - ay;
    }
}

// --- 5) geo: 7x7 windowed variance of disp (count_include_pad=False) ---
__global__ __launch_bounds__(256) void geo_kernel(
    const float* __restrict__ dp, float* __restrict__ geo)
{
    int tid = blockIdx.x * 256 + threadIdx.x;   // 65536 = 2*8*4096
    int n = tid & 4095; int bk = tid >> 12;     // bk = b*8+k
    int b = bk >> 3; int k = bk & 7;
    int h = n >> 6, w = n & 63;
    const float* dpx = dp + ((size_t)(bk * 2 + 0)) * 4096;
    const float* dpy = dp + ((size_t)(bk * 2 + 1)) * 4096;
    float sx = 0, sy = 0, sxx = 0, syy = 0, cnt = 0;
    #pragma unroll
    for (int dy = -3; dy <= 3; dy++) {
        int hh = h + dy; if ((unsigned)hh >= 64u) continue;
        #pragma unroll
        for (int dx = -3; dx <= 3; dx++) {
            int ww = w + dx; if ((unsigned)ww >= 64u) continue;
            int nn = (hh << 6) + ww;
            float vx = dpx[nn], vy = dpy[nn];
            sx += vx; sy += vy; sxx += vx * vx; syy += vy * vy; cnt += 1.f;
        }
    }
    float inv = 1.f / cnt;
    float mx = sx * inv, my = sy * inv;
    float varx = fmaxf(sxx * inv - mx * mx, 0.f);
    float vary = fmaxf(syy * inv - my * my, 0.f);
    geo[((size_t)(b * 4096 + n)) * 8 + k] = 1.f / (1.f + 100.f * (varx + vary));
}

// --- 6) softmax refine: refined_warp + conf -> d_out ---
__global__ __launch_bounds__(256) void refine_kernel(
    const float* __restrict__ tkv, const float* __restrict__ geo,
    const float* __restrict__ tkp, const float* __restrict__ gwp,
    const float* __restrict__ tpp, float* __restrict__ out)
{
    int tid = blockIdx.x * 256 + threadIdx.x;   // 0..8191 == b*4096+n
    float gw = fminf(fmaxf(gwp[0], 0.f), 2.f);
    float invt = 1.f / tpp[0];
    size_t base = (size_t)tid * 8;
    float cb[8], vv[8];
    float mx = -INFINITY;
    #pragma unroll
    for (int k = 0; k < 8; k++) { vv[k] = tkv[base + k]; cb[k] = vv[k] + gw * geo[base + k]; mx = fmaxf(mx, cb[k]); }
    float e[8], se = 0;
    #pragma unroll
    for (int k = 0; k < 8; k++) { e[k] = __expf((cb[k] - mx) * invt); se += e[k]; }
    float wx = 0, wy = 0, cf = 0; float inv = 1.f / se;
    #pragma unroll
    for (int k = 0; k < 8; k++) {
        float s = e[k] * inv;
        wx += s * tkp[(base + k) * 2 + 0];
        wy += s * tkp[(base + k) * 2 + 1];
        cf += s * vv[k];
    }
    out[(size_t)tid * 2 + 0] = wx;
    out[(size_t)tid * 2 + 1] = wy;
    out[16384 + tid] = cf;
}

// --- 7) weighted affine: 12 sums per batch (double) ---
__global__ __launch_bounds__(256) void affine_reduce(
    const float* __restrict__ posA, const float* __restrict__ out, double* __restrict__ sums)
{
    int b = blockIdx.x; int t = threadIdx.x;
    double acc[12] = {0,0,0,0,0,0,0,0,0,0,0,0};
    for (int n = t; n < 4096; n += 256) {
        size_t idx = (size_t)b * 4096 + n;
        float x = posA[idx * 2], y = posA[idx * 2 + 1];
        float dx = out[idx * 2], dy = out[idx * 2 + 1];
        float c = out[16384 + idx];
        double cd = (double)c;
        double cx = cd * x, cy = cd * y;
        acc[0] += cx * x;  acc[1] += cx * y;  acc[2] += cy * y;
        acc[3] += cx;      acc[4] += cy;      acc[5] += cd;
        acc[6] += cx * dx; acc[7] += cy * dx; acc[8] += cd * dx;
        acc[9] += cx * dy; acc[10] += cy * dy; acc[11] += cd * dy;
    }
    __shared__ double red[256];
    for (int s = 0; s < 12; s++) {
        red[t] = acc[s]; __syncthreads();
        for (int off = 128; off > 0; off >>= 1) {
            if (t < off) red[t] += red[t + off];
            __syncthreads();
        }
        if (t == 0) sums[b * 12 + s] = red[0];
        __syncthreads();
    }
}

// --- 8) closed-form 3x3 solve (AtWA is block-diagonal), H_mat -> d_out ---
__global__ void affine_solve(const double* __restrict__ sums, float* __restrict__ out)
{
    int t = threadIdx.x;
    if (t >= 2) return;
    int b = t;
    const double* s = sums + b * 12;
    double den = s[5] > 1e-6 ? s[5] : 1e-6;
    double g00 = s[0] / den + 1e-4, g01 = s[1] / den, g02 = s[3] / den;
    double g11 = s[2] / den + 1e-4, g12 = s[4] / den;
    double g22 = s[5] / den + 1e-4;
    double bx0 = s[6] / den, bx1 = s[7] / den, bx2 = s[8] / den;
    double by0 = s[9] / den, by1 = s[10] / den, by2 = s[11] / den;
    double c00 = g11 * g22 - g12 * g12;
    double c01 = g02 * g12 - g01 * g22;
    double c02 = g01 * g12 - g02 * g11;
    double det = g00 * c00 + g01 * c01 + g02 * c02;
    double id = 1.0 / det;
    double i00 = c00 * id, i01 = c01 * id, i02 = c02 * id;
    double i11 = (g00 * g22 - g02 * g02) * id, i12 = (g01 * g02 - g00 * g12) * id;
    double i22 = (g00 * g11 - g01 * g01) * id;
    double a_ = i00 * bx0 + i01 * bx1 + i02 * bx2;
    double b_ = i01 * bx0 + i11 * bx1 + i12 * bx2;
    double c_ = i02 * bx0 + i12 * bx1 + i22 * bx2;
    double d_ = i00 * by0 + i01 * by1 + i02 * by2;
    double e_ = i01 * by0 + i11 * by1 + i12 * by2;
    double f_ = i02 * by0 + i12 * by1 + i22 * by2;
    float* o = out + 24576 + b * 9;
    o[0] = (float)a_; o[1] = (float)b_; o[2] = (float)c_;
    o[3] = (float)d_; o[4] = (float)e_; o[5] = (float)f_;
    o[6] = 0.f; o[7] = 0.f; o[8] = 1.f;
}

extern "C" void kernel_launch(void* const* d_in, const int* in_sizes, int n_in,
                              void* d_out, int out_size, void* d_ws, size_t ws_size,
                              hipStream_t stream) {
    const float* fA = (const float*)d_in[0];
    const float* fB = (const float*)d_in[1];
    const float* pA = (const float*)d_in[2];
    const float* pB = (const float*)d_in[3];
    const float* db = (const float*)d_in[4];
    const float* gw = (const float*)d_in[5];
    const float* tp = (const float*)d_in[6];

    float* ws   = (float*)d_ws;
    float* out  = (float*)d_out;
    float* S    = ws;
    float* u    = ws + OFF_U;
    float* v    = ws + OFF_V;
    float* rn   = ws + OFF_RN;
    float* pm   = ws + OFF_PM;
    float* ps   = ws + OFF_PS;
    float* tkv  = ws + OFF_TKV;
    float* tkp  = ws + OFF_TKP;
    float* dp   = ws + OFF_DP;
    float* geo  = ws + OFF_GEO;
    double* sums = (double*)(ws + OFF_SUM);

    // u,v are contiguous; zero both (v must be 0 at iteration 1)
    hipMemsetAsync(u, 0, (size_t)(2 * 4097 * 2) * sizeof(float), stream);

    norms_kernel<<<4096, 256, 0, stream>>>(fA, fB, rn);
    gemm_scores<<<dim3(64, 64, 2), 256, 0, stream>>>(fA, fB, rn, tp, S);

    for (int it = 0; it < 5; it++) {
        sink_u<<<2 * 4097, 256, 0, stream>>>(S, u, v, db);
        sink_vA<<<dim3(16, 16, 2), 256, 0, stream>>>(S, u, pm, ps);
        sink_vB<<<dim3(17, 1, 2), 256, 0, stream>>>(pm, ps, u, v, db);
    }

    topk_kernel<<<8192, 256, 0, stream>>>(S, u, v, pA, pB, tkv, tkp, dp);
    geo_kernel<<<256, 256, 0, stream>>>(dp, geo);
    refine_kernel<<<32, 256, 0, stream>>>(tkv, geo, tkp, gw, tp, out);
    affine_reduce<<<2, 256, 0, stream>>>(pA, out, sums);
    affine_solve<<<1, 64, 0, stream>>>(sums, out);
}